// Round 7
// baseline (158.333 us; speedup 1.0000x reference)
//
#include <hip/hip_runtime.h>
#include <math.h>

#define N_VEC 65536
#define D 64
#define K 1024
#define VQ_EPS 1e-10f

typedef __attribute__((ext_vector_type(8))) short s16x8;   // 8 bf16 = 4 VGPR
typedef __attribute__((ext_vector_type(4))) float f32x4;   // MFMA acc

#define MFMA(a, b, c) __builtin_amdgcn_mfma_f32_16x16x32_bf16((a), (b), (c), 0, 0, 0)

__device__ __forceinline__ unsigned short bf16_rne(float f) {
    unsigned u = __float_as_uint(f);
    u += 0x7fff + ((u >> 16) & 1);
    return (unsigned short)(u >> 16);
}
__device__ __forceinline__ float bf16_f32(unsigned short h) {
    return __uint_as_float(((unsigned)h) << 16);
}

// async global->LDS DMA, 16 B per lane; LDS dest = wave-uniform base + lane*16
__device__ __forceinline__ void async_load16(const void* g, void* lds_generic) {
    __builtin_amdgcn_global_load_lds(
        (const __attribute__((address_space(1))) unsigned int*)g,
        (__attribute__((address_space(3))) unsigned int*)lds_generic, 16, 0, 0);
}

// ---------------------------------------------------------------------------
// Kernel A: pack embeddings into MFMA-fragment order (verified layout).
// Chunk id = ct*16 + g*4 + bg (bg: 0=hi k0-31, 1=hi k32-63, 2=lo k0-31,
// 3=lo k32-63). Slot q*16+c in a chunk = 16 B = 8 bf16 of code g*16+c.
// enorm stores -0.5*||e||^2; counts[K] doubles as completion counter.
// 64 blocks x 64 threads (verified in R4/R6) to cut pack latency vs 16x256.
// ---------------------------------------------------------------------------
__global__ void pack_e_kernel(const float* __restrict__ emb,
                              uint4* __restrict__ ep4,
                              float* __restrict__ enorm,
                              int* __restrict__ counts) {
    int gid = blockIdx.x * 64 + threadIdx.x;       // 0..4095
    int code = gid >> 2, tq = gid & 3;             // tq: k-quarter (16 elems)
    const float* row = emb + (size_t)code * D + tq * 16;
    unsigned int hi[8], lo[8];
    float nrm = 0.f;
#pragma unroll
    for (int i = 0; i < 4; ++i) {
        float4 v = *reinterpret_cast<const float4*>(row + i * 4);
        nrm += v.x * v.x + v.y * v.y + v.z * v.z + v.w * v.w;
        float f[4] = {v.x, v.y, v.z, v.w};
        unsigned short hh[4], ll[4];
#pragma unroll
        for (int j = 0; j < 4; ++j) {
            hh[j] = bf16_rne(f[j]);
            ll[j] = bf16_rne(f[j] - bf16_f32(hh[j]));
        }
        hi[i * 2 + 0] = (unsigned)hh[0] | ((unsigned)hh[1] << 16);
        hi[i * 2 + 1] = (unsigned)hh[2] | ((unsigned)hh[3] << 16);
        lo[i * 2 + 0] = (unsigned)ll[0] | ((unsigned)ll[1] << 16);
        lo[i * 2 + 1] = (unsigned)ll[2] | ((unsigned)ll[3] << 16);
    }
    const int ct = code >> 6, g = (code >> 4) & 3, c = code & 15;
#pragma unroll
    for (int h = 0; h < 2; ++h) {
        int gran = 2 * tq + h;               // 0..7
        int bg = gran >> 2, qq = gran & 3;
        ep4[(size_t)(ct * 16 + g * 4 + bg) * 64 + qq * 16 + c] =
            make_uint4(hi[h * 4], hi[h * 4 + 1], hi[h * 4 + 2], hi[h * 4 + 3]);
        int granl = 8 + gran;                // lo: bg 2..3
        bg = granl >> 2; qq = granl & 3;
        ep4[(size_t)(ct * 16 + g * 4 + bg) * 64 + qq * 16 + c] =
            make_uint4(lo[h * 4], lo[h * 4 + 1], lo[h * 4 + 2], lo[h * 4 + 3]);
    }
    nrm += __shfl_xor(nrm, 1, 64);
    nrm += __shfl_xor(nrm, 2, 64);
    if (tq == 0) enorm[code] = -0.5f * nrm;        // pre-negated half-norm
    if (gid <= K) counts[gid] = 0;                 // counts[K] = completion ctr
}

// ---------------------------------------------------------------------------
// Kernel B: BYTE-EXACT R0 main loop (the measured-best 68.5 us core).
// R4-R6 post-mortem: every regressed variant carried #pragma unroll 1 and/or
// dynamic tile indexing, defeating the compiler's full unroll + constant
// addressing of the 16-iteration loop. This restores the R0 loop exactly
// (constant trip count, no pragma, ascending tiles, strict-> update,
// __syncthreads per tile, -||e||^2/2 as MFMA C operand), and keeps only the
// two verified-out-of-loop wins: fused perplexity epilogue (saves a launch,
// ~16 us of fixed overhead, verified R6) and pre-negated enorm (one fewer
// VALU mul per group; addresses unchanged).
// C-layout: col(code)=lane&15, row(vec)=(lane>>4)*4+reg (m89-verified).
// ---------------------------------------------------------------------------
__global__ void __launch_bounds__(256, 4)
vq_kernel(const float* __restrict__ x,
          const float* __restrict__ emb,
          const uint4* __restrict__ ep4,
          const float* __restrict__ enormp,   // holds -0.5*||e||^2
          int* __restrict__ counts,           // K+1 ints; [K] = completion ctr
          float* __restrict__ out) {
    __shared__ __align__(16) unsigned short bt[2][64 * 128];   // 2 x 16 KB B
    __shared__ __align__(16) float en[K];                      // 4 KB norms
    __shared__ int   bks[64];
    __shared__ float ws[4];
    __shared__ int   amLast;

    const int t    = threadIdx.x;
    const int w    = t >> 6;
    const int lane = t & 63;
    const int q    = lane >> 4;
    const int c    = lane & 15;
    const int vb   = blockIdx.x * 64;

    // ---- all 1024 norms -> LDS (one float4 per thread) ----
    reinterpret_cast<float4*>(en)[t] = reinterpret_cast<const float4*>(enormp)[t];

    // ---- A-frags: 16 vectors/wave, bf16 hi/lo (16 VGPR) ----
    s16x8 Ah0, Ah1, Al0, Al1;
#define LOAD_A(h, AH, AL)                                                      \
    {                                                                          \
        const float* xr = x + (size_t)(vb + w * 16 + c) * D + (h) * 32 + q * 8;\
        float4 u0 = *reinterpret_cast<const float4*>(xr);                      \
        float4 u1 = *reinterpret_cast<const float4*>(xr + 4);                  \
        float f[8] = {u0.x, u0.y, u0.z, u0.w, u1.x, u1.y, u1.z, u1.w};         \
        s16x8 hiv, lov;                                                        \
        _Pragma("unroll") for (int j = 0; j < 8; ++j) {                        \
            unsigned short hb = bf16_rne(f[j]);                                \
            hiv[j] = (short)hb;                                                \
            lov[j] = (short)bf16_rne(f[j] - bf16_f32(hb));                     \
        }                                                                      \
        AH = hiv; AL = lov;                                                    \
    }
    LOAD_A(0, Ah0, Al0)
    LOAD_A(1, Ah1, Al1)
#undef LOAD_A

    // ---- prologue: DMA tile 0's chunks (wave w -> chunks w*4..w*4+3) ----
    {
        const char* gbase = (const char*)ep4 + (size_t)(w * 4) * 1024 + lane * 16;
        char* lbase = (char*)bt[0] + (w * 4) * 1024;
#pragma unroll
        for (int i = 0; i < 4; ++i)
            async_load16(gbase + i * 1024, lbase + i * 1024);
    }

    float best[4];
    int   bk_[4];
#pragma unroll
    for (int s = 0; s < 4; ++s) { best[s] = -3.4e38f; bk_[s] = 0; }

    for (int ct = 0; ct < 16; ++ct) {
        __syncthreads();   // vmcnt(0)+barrier: tile ct ready in bt[ct&1];
                           // everyone done reading bt[(ct+1)&1]

        if (ct < 15) {     // DMA next tile into the other buffer
            const char* gbase = (const char*)ep4
                + (size_t)((ct + 1) * 16 + w * 4) * 1024 + lane * 16;
            char* lbase = (char*)bt[(ct + 1) & 1] + (w * 4) * 1024;
#pragma unroll
            for (int i = 0; i < 4; ++i)
                async_load16(gbase + i * 1024, lbase + i * 1024);
        }

        const unsigned short* bufS = bt[ct & 1];
#pragma unroll
        for (int g = 0; g < 4; ++g) {
            // canonical conflict-free b128 reads: chunk*512 shorts + lane*8
            s16x8 Bh0 = *reinterpret_cast<const s16x8*>(bufS + (g * 4 + 0) * 512 + lane * 8);
            s16x8 Bh1 = *reinterpret_cast<const s16x8*>(bufS + (g * 4 + 1) * 512 + lane * 8);
            s16x8 Bl0 = *reinterpret_cast<const s16x8*>(bufS + (g * 4 + 2) * 512 + lane * 8);
            s16x8 Bl1 = *reinterpret_cast<const s16x8*>(bufS + (g * 4 + 3) * 512 + lane * 8);

            const int codeG = ct * 64 + g * 16 + c;
            const float e2 = en[codeG];            // -||e||^2/2 as C operand
            f32x4 acc = (f32x4){e2, e2, e2, e2};

            acc = MFMA(Ah0, Bh0, acc);
            acc = MFMA(Ah1, Bh1, acc);
            acc = MFMA(Ah0, Bl0, acc);
            acc = MFMA(Ah1, Bl1, acc);
            acc = MFMA(Al0, Bh0, acc);
            acc = MFMA(Al1, Bh1, acc);

            // score = dot - enc/2; argMAX(score) == argMIN(dist), exact ties
#pragma unroll
            for (int r = 0; r < 4; ++r) {
                if (acc[r] > best[r]) { best[r] = acc[r]; bk_[r] = codeG; }
            }
        }
    }

    // ---- reduce over the 16 code-columns (max score; tie -> smaller idx) ----
#pragma unroll
    for (int m = 1; m <= 8; m <<= 1)
#pragma unroll
        for (int s = 0; s < 4; ++s) {
            float ob = __shfl_xor(best[s], m, 64);
            int   ok = __shfl_xor(bk_[s], m, 64);
            if (ob > best[s] || (ob == best[s] && ok < bk_[s])) {
                best[s] = ob; bk_[s] = ok;
            }
        }
    if (c == 0) {
#pragma unroll
        for (int r = 0; r < 4; ++r) {
            int lv = w * 16 + q * 4 + r;
            int kk = bk_[r];
            bks[lv] = kk;
            atomicAdd(&counts[kk], 1);
        }
    }
    __syncthreads();

    // ---- gather winning rows -> out (exact fp32) ----
    {
        int vec = t >> 2, part = t & 3;
        int kk = bks[vec];
        const float4* src = reinterpret_cast<const float4*>(emb + (size_t)kk * D) + part * 4;
        float4* dst = reinterpret_cast<float4*>(out + (size_t)(vb + vec) * D) + part * 4;
#pragma unroll
        for (int j = 0; j < 4; ++j) dst[j] = src[j];
    }

    // ---- last finishing block computes perplexity from counts (R6-verified) --
    __syncthreads();
    if (t == 0) {
        __threadfence();
        amLast = (atomicAdd(&counts[K], 1) == (int)gridDim.x - 1);
    }
    __syncthreads();
    if (amLast) {
        float s = 0.f;
#pragma unroll
        for (int i = 0; i < 4; ++i) {
            int cnt = __hip_atomic_load(&counts[t + i * 256], __ATOMIC_RELAXED,
                                        __HIP_MEMORY_SCOPE_AGENT);
            float p = (float)cnt * (1.0f / (float)N_VEC);
            s += p * logf(p + VQ_EPS);
        }
#pragma unroll
        for (int m = 1; m < 64; m <<= 1) s += __shfl_xor(s, m, 64);
        if (lane == 0) ws[w] = s;
        __syncthreads();
        if (t == 0) out[(size_t)N_VEC * D] = expf(-(ws[0] + ws[1] + ws[2] + ws[3]));
    }
}

// ---------------------------------------------------------------------------
extern "C" void kernel_launch(void* const* d_in, const int* in_sizes, int n_in,
                              void* d_out, int out_size, void* d_ws, size_t ws_size,
                              hipStream_t stream) {
    const float* x   = (const float*)d_in[0];   // [65536, 64] fp32
    const float* emb = (const float*)d_in[1];   // [1024, 64] fp32
    float* out = (float*)d_out;                 // 4194304 quantized + 1 perplexity

    uint4* ep     = (uint4*)d_ws;                                      // 256 KB packed
    float* enorm  = (float*)((char*)d_ws + (size_t)K * 128 * 2);       // 4 KB (-0.5*||e||^2)
    int*   counts = (int*)((char*)enorm + K * sizeof(float));          // K+1 ints

    pack_e_kernel<<<64, 64, 0, stream>>>(emb, ep, enorm, counts);
    vq_kernel<<<N_VEC / 64, 256, 0, stream>>>(x, emb, ep, enorm, counts, out);
}

// Round 8
// 131.093 us; speedup vs baseline: 1.2078x; 1.2078x over previous
//
#include <hip/hip_runtime.h>
#include <math.h>

#define N_VEC 65536
#define D 64
#define K 1024
#define VQ_EPS 1e-10f

typedef __attribute__((ext_vector_type(8))) short s16x8;   // 8 bf16 = 4 VGPR
typedef __attribute__((ext_vector_type(4))) float f32x4;   // MFMA acc

#define MFMA(a, b, c) __builtin_amdgcn_mfma_f32_16x16x32_bf16((a), (b), (c), 0, 0, 0)

__device__ __forceinline__ unsigned short bf16_rne(float f) {
    unsigned u = __float_as_uint(f);
    u += 0x7fff + ((u >> 16) & 1);
    return (unsigned short)(u >> 16);
}
__device__ __forceinline__ float bf16_f32(unsigned short h) {
    return __uint_as_float(((unsigned)h) << 16);
}

// async global->LDS DMA, 16 B per lane; LDS dest = wave-uniform base + lane*16
__device__ __forceinline__ void async_load16(const void* g, void* lds_generic) {
    __builtin_amdgcn_global_load_lds(
        (const __attribute__((address_space(1))) unsigned int*)g,
        (__attribute__((address_space(3))) unsigned int*)lds_generic, 16, 0, 0);
}

// ---------------------------------------------------------------------------
// Kernel A: pack embeddings into MFMA-fragment order (R0-verified layout and
// body). Chunk id = ct*16 + g*4 + bg (bg: 0=hi k0-31, 1=hi k32-63,
// 2=lo k0-31, 3=lo k32-63). Slot q*16+c in a chunk = 16 B = 8 bf16 of code
// g*16+c. fp32 norms (positive, as in R0) + zero counts.
// Only delta vs R0: 64 blocks x 64 threads (same gid mapping) so the
// scattered stores spread over 64 CUs instead of 16.
// ---------------------------------------------------------------------------
__global__ void pack_e_kernel(const float* __restrict__ emb,
                              uint4* __restrict__ ep4,
                              float* __restrict__ enorm,
                              int* __restrict__ counts) {
    int gid = blockIdx.x * 64 + threadIdx.x;       // 0..4095
    int code = gid >> 2, tq = gid & 3;             // tq: k-quarter (16 elems)
    const float* row = emb + (size_t)code * D + tq * 16;
    unsigned int hi[8], lo[8];
    float nrm = 0.f;
#pragma unroll
    for (int i = 0; i < 4; ++i) {
        float4 v = *reinterpret_cast<const float4*>(row + i * 4);
        nrm += v.x * v.x + v.y * v.y + v.z * v.z + v.w * v.w;
        float f[4] = {v.x, v.y, v.z, v.w};
        unsigned short hh[4], ll[4];
#pragma unroll
        for (int j = 0; j < 4; ++j) {
            hh[j] = bf16_rne(f[j]);
            ll[j] = bf16_rne(f[j] - bf16_f32(hh[j]));
        }
        hi[i * 2 + 0] = (unsigned)hh[0] | ((unsigned)hh[1] << 16);
        hi[i * 2 + 1] = (unsigned)hh[2] | ((unsigned)hh[3] << 16);
        lo[i * 2 + 0] = (unsigned)ll[0] | ((unsigned)ll[1] << 16);
        lo[i * 2 + 1] = (unsigned)ll[2] | ((unsigned)ll[3] << 16);
    }
    const int ct = code >> 6, g = (code >> 4) & 3, c = code & 15;
#pragma unroll
    for (int h = 0; h < 2; ++h) {
        int gran = 2 * tq + h;               // 0..7
        int bg = gran >> 2, q = gran & 3;
        ep4[(size_t)(ct * 16 + g * 4 + bg) * 64 + q * 16 + c] =
            make_uint4(hi[h * 4], hi[h * 4 + 1], hi[h * 4 + 2], hi[h * 4 + 3]);
        int granl = 8 + gran;                // lo: bg 2..3
        bg = granl >> 2; q = granl & 3;
        ep4[(size_t)(ct * 16 + g * 4 + bg) * 64 + q * 16 + c] =
            make_uint4(lo[h * 4], lo[h * 4 + 1], lo[h * 4 + 2], lo[h * 4 + 3]);
    }
    nrm += __shfl_xor(nrm, 1, 64);
    nrm += __shfl_xor(nrm, 2, 64);
    if (tq == 0) enorm[code] = nrm;                // positive, exactly as R0
    if (gid < K) counts[gid] = 0;
}

// ---------------------------------------------------------------------------
// Kernel B: BYTE-EXACT R0 vq kernel (the measured 68.5 us core). No fence,
// no completion counter, no fused epilogue — R7 post-mortem: the fused
// perplexity epilogue's device-scope __threadfence forces a non-coherent-XCD
// L2 writeback per block (WRITE_SIZE 18.4 -> 29 MB, vq +40 us in every
// fused round R1-R7). Cross-XCD communication stays OUT of this kernel.
//  - Wave owns 16 vectors; A = 4 named s16x8; B: 2 x 16 KB LDS dbuf via
//    global_load_lds; 4 blocks/CU, 16 waves/CU; acc init = -enc/2 (C
//    operand); argMAX of score = dot - enc/2; strict >, ascending order.
// C-layout: col(code)=lane&15, row(vec)=(lane>>4)*4+reg (m89-verified).
// ---------------------------------------------------------------------------
__global__ void __launch_bounds__(256, 4)
vq_kernel(const float* __restrict__ x,
          const float* __restrict__ emb,
          const uint4* __restrict__ ep4,
          const float* __restrict__ enormp,
          int* __restrict__ counts,
          float* __restrict__ out) {
    __shared__ __align__(16) unsigned short bt[2][64 * 128];   // 2 x 16 KB B
    __shared__ __align__(16) float en[K];                      // 4 KB norms
    __shared__ int bks[64];

    const int t    = threadIdx.x;
    const int w    = t >> 6;
    const int lane = t & 63;
    const int q    = lane >> 4;
    const int c    = lane & 15;
    const int vb   = blockIdx.x * 64;

    // ---- all 1024 enorms -> LDS (one float4 per thread) ----
    reinterpret_cast<float4*>(en)[t] = reinterpret_cast<const float4*>(enormp)[t];

    // ---- A-frags: 16 vectors/wave, bf16 hi/lo, 4 named s16x8 (16 VGPRs) ----
    s16x8 Ah0, Ah1, Al0, Al1;
#define LOAD_A(h, AH, AL)                                                      \
    {                                                                          \
        const float* xr = x + (size_t)(vb + w * 16 + c) * D + (h) * 32 + q * 8;\
        float4 u0 = *reinterpret_cast<const float4*>(xr);                      \
        float4 u1 = *reinterpret_cast<const float4*>(xr + 4);                  \
        float f[8] = {u0.x, u0.y, u0.z, u0.w, u1.x, u1.y, u1.z, u1.w};         \
        s16x8 hiv, lov;                                                        \
        _Pragma("unroll") for (int j = 0; j < 8; ++j) {                        \
            unsigned short hb = bf16_rne(f[j]);                                \
            hiv[j] = (short)hb;                                                \
            lov[j] = (short)bf16_rne(f[j] - bf16_f32(hb));                     \
        }                                                                      \
        AH = hiv; AL = lov;                                                    \
    }
    LOAD_A(0, Ah0, Al0)
    LOAD_A(1, Ah1, Al1)
#undef LOAD_A

    // ---- prologue: DMA tile 0's chunks (wave w -> chunks w*4..w*4+3) ----
    {
        const char* gbase = (const char*)ep4 + (size_t)(w * 4) * 1024 + lane * 16;
        char* lbase = (char*)bt[0] + (w * 4) * 1024;
#pragma unroll
        for (int i = 0; i < 4; ++i)
            async_load16(gbase + i * 1024, lbase + i * 1024);
    }

    float best[4];
    int   bk_[4];
#pragma unroll
    for (int s = 0; s < 4; ++s) { best[s] = -3.4e38f; bk_[s] = 0; }

    for (int ct = 0; ct < 16; ++ct) {
        __syncthreads();   // vmcnt(0)+barrier: tile ct ready in bt[ct&1];
                           // everyone done reading bt[(ct+1)&1]

        if (ct < 15) {     // DMA next tile into the other buffer
            const char* gbase = (const char*)ep4
                + (size_t)((ct + 1) * 16 + w * 4) * 1024 + lane * 16;
            char* lbase = (char*)bt[(ct + 1) & 1] + (w * 4) * 1024;
#pragma unroll
            for (int i = 0; i < 4; ++i)
                async_load16(gbase + i * 1024, lbase + i * 1024);
        }

        const unsigned short* bufS = bt[ct & 1];
#pragma unroll
        for (int g = 0; g < 4; ++g) {
            // canonical conflict-free b128 reads: chunk*512 shorts + lane*8
            s16x8 Bh0 = *reinterpret_cast<const s16x8*>(bufS + (g * 4 + 0) * 512 + lane * 8);
            s16x8 Bh1 = *reinterpret_cast<const s16x8*>(bufS + (g * 4 + 1) * 512 + lane * 8);
            s16x8 Bl0 = *reinterpret_cast<const s16x8*>(bufS + (g * 4 + 2) * 512 + lane * 8);
            s16x8 Bl1 = *reinterpret_cast<const s16x8*>(bufS + (g * 4 + 3) * 512 + lane * 8);

            const int codeG = ct * 64 + g * 16 + c;
            const float e2 = -0.5f * en[codeG];
            f32x4 acc = (f32x4){e2, e2, e2, e2};   // fold -enc/2 into C operand

            acc = MFMA(Ah0, Bh0, acc);
            acc = MFMA(Ah1, Bh1, acc);
            acc = MFMA(Ah0, Bl0, acc);
            acc = MFMA(Ah1, Bl1, acc);
            acc = MFMA(Al0, Bh0, acc);
            acc = MFMA(Al1, Bh1, acc);

            // score = dot - enc/2; argMAX(score) == argMIN(dist), exact ties
#pragma unroll
            for (int r = 0; r < 4; ++r) {
                if (acc[r] > best[r]) { best[r] = acc[r]; bk_[r] = codeG; }
            }
        }
    }

    // ---- reduce over the 16 code-columns (max score; tie -> smaller idx) ----
#pragma unroll
    for (int m = 1; m <= 8; m <<= 1)
#pragma unroll
        for (int s = 0; s < 4; ++s) {
            float ob = __shfl_xor(best[s], m, 64);
            int   ok = __shfl_xor(bk_[s], m, 64);
            if (ob > best[s] || (ob == best[s] && ok < bk_[s])) {
                best[s] = ob; bk_[s] = ok;
            }
        }
    if (c == 0) {
#pragma unroll
        for (int r = 0; r < 4; ++r) {
            int lv = w * 16 + q * 4 + r;
            int kk = bk_[r];
            bks[lv] = kk;
            atomicAdd(&counts[kk], 1);
        }
    }
    __syncthreads();

    // ---- gather winning rows -> out (exact fp32) ----
    {
        int vec = t >> 2, part = t & 3;
        int kk = bks[vec];
        const float4* src = reinterpret_cast<const float4*>(emb + (size_t)kk * D) + part * 4;
        float4* dst = reinterpret_cast<float4*>(out + (size_t)(vb + vec) * D) + part * 4;
#pragma unroll
        for (int j = 0; j < 4; ++j) dst[j] = src[j];
    }
}

// ---------------------------------------------------------------------------
// Kernel C: perplexity = exp(-sum p log(p+eps)), p = counts/N. 256 threads.
// Separate launch (exactly as R0): keeps device-scope fencing OUT of vq.
// ---------------------------------------------------------------------------
__global__ void perplexity_kernel(const int* __restrict__ counts,
                                  float* __restrict__ outp) {
    int t = threadIdx.x;
    float s = 0.f;
#pragma unroll
    for (int i = 0; i < 4; ++i) {
        float p = (float)counts[t + i * 256] * (1.0f / (float)N_VEC);
        s += p * logf(p + VQ_EPS);
    }
#pragma unroll
    for (int m = 1; m < 64; m <<= 1) s += __shfl_xor(s, m, 64);
    __shared__ float ws[4];
    if ((t & 63) == 0) ws[t >> 6] = s;
    __syncthreads();
    if (t == 0) *outp = expf(-(ws[0] + ws[1] + ws[2] + ws[3]));
}

// ---------------------------------------------------------------------------
extern "C" void kernel_launch(void* const* d_in, const int* in_sizes, int n_in,
                              void* d_out, int out_size, void* d_ws, size_t ws_size,
                              hipStream_t stream) {
    const float* x   = (const float*)d_in[0];   // [65536, 64] fp32
    const float* emb = (const float*)d_in[1];   // [1024, 64] fp32
    float* out = (float*)d_out;                 // 4194304 quantized + 1 perplexity

    uint4* ep     = (uint4*)d_ws;                                      // 256 KB packed
    float* enorm  = (float*)((char*)d_ws + (size_t)K * 128 * 2);       // 4 KB
    int*   counts = (int*)((char*)enorm + K * sizeof(float));          // 4 KB

    pack_e_kernel<<<64, 64, 0, stream>>>(emb, ep, enorm, counts);
    vq_kernel<<<N_VEC / 64, 256, 0, stream>>>(x, emb, ep, enorm, counts, out);
    perplexity_kernel<<<1, 256, 0, stream>>>(counts, out + (size_t)N_VEC * D);
}